// Round 1
// baseline (85164.105 us; speedup 1.0000x reference)
//
#include <hip/hip_runtime.h>
#include <math.h>

#define NROWS 4096
#define DZ    128
#define DH    512
#define VOC   64
#define DE    128
#define MAXLEN 128
#define PAD_T 0
#define SOS_T 1
#define EOS_T 2

// ---------------- transpose: in [R][C] -> out [C][R] ----------------
__global__ void transpose_k(const float* __restrict__ in, float* __restrict__ out,
                            int R, int C) {
  __shared__ float tile[32][33];
  int cb = blockIdx.x * 32, rb = blockIdx.y * 32;
  int tx = threadIdx.x, ty = threadIdx.y;  // blockDim (32,8)
  #pragma unroll
  for (int i = ty; i < 32; i += 8)
    tile[i][tx] = in[(size_t)(rb + i) * C + (cb + tx)];
  __syncthreads();
  #pragma unroll
  for (int i = ty; i < 32; i += 8)
    out[(size_t)(cb + i) * R + (rb + tx)] = tile[tx][i];
}

// ---------------- init: h0 = Z @ z2h_w^T + b; state init ----------------
__global__ __launch_bounds__(256) void init_kernel(
    const float* __restrict__ Z, const float* __restrict__ z2hT,
    const float* __restrict__ z2h_b,
    float* __restrict__ h1, float* __restrict__ h2, float* __restrict__ h3,
    int* __restrict__ tok, int* __restrict__ eos, int* __restrict__ outi) {
  int lane = threadIdx.x & 63;
  int wave = __builtin_amdgcn_readfirstlane((int)(threadIdx.x >> 6));
  int r = blockIdx.x * 4 + wave;          // grid.x = NROWS/4
  int j = blockIdx.y * 64 + lane;         // grid.y = DH/64
  float acc = z2h_b[j];
  const float* zr = Z + (size_t)r * DZ;   // zr[k] is wave-uniform -> s_load
  #pragma unroll 4
  for (int k = 0; k < DZ; ++k)
    acc = fmaf(zr[k], z2hT[(size_t)k * DH + j], acc);
  size_t o = (size_t)r * DH + j;
  h1[o] = acc; h2[o] = acc; h3[o] = acc;
  if (blockIdx.y == 0 && lane == 0) {
    tok[r] = SOS_T;
    eos[r] = 0;
    outi[(size_t)r * MAXLEN] = SOS_T;               // X_gen[:,0] = SOS
    outi[(size_t)NROWS * MAXLEN + r] = MAXLEN;      // seq_lens init
  }
}

// ---------------- fused GRU cell layer ----------------
// lane -> gate unit j (64 per wave), wave -> 16-row block.
// Weights pre-transposed: WiT [KX][3*DH], WhT [DH][3*DH] (coalesced over j).
// Activations read as wave-uniform scalar loads (SGPR operand of v_fmac).
template <int KX, bool EMB>
__global__ __launch_bounds__(256) void gru_kernel(
    const float* __restrict__ Xin,    // [NROWS][KX], or emb [VOC][DE] if EMB
    const int* __restrict__ tok,      // token feed (EMB only)
    const float* __restrict__ Hprev,  // [NROWS][DH] this layer's prev state
    const float* __restrict__ WiT, const float* __restrict__ WhT,
    const float* __restrict__ bi, const float* __restrict__ bh,
    float* __restrict__ Hnew) {
  constexpr int R = 16;
  int lane = threadIdx.x & 63;
  int wave = __builtin_amdgcn_readfirstlane((int)(threadIdx.x >> 6));
  int r0 = blockIdx.x * (4 * R) + wave * R;  // grid.x = NROWS/64
  int j  = blockIdx.y * 64 + lane;           // grid.y = DH/64

  float accr[R], accz[R], accin[R], acchn[R];
  {
    float br  = bi[j]        + bh[j];
    float bz  = bi[DH + j]   + bh[DH + j];
    float bin = bi[2*DH + j];
    float bhn = bh[2*DH + j];
    #pragma unroll
    for (int r = 0; r < R; ++r) { accr[r]=br; accz[r]=bz; accin[r]=bin; acchn[r]=bhn; }
  }

  // uniform row offsets (SGPR)
  int xoff[R];
  if (EMB) {
    #pragma unroll
    for (int r = 0; r < R; ++r) xoff[r] = tok[r0 + r] * DE;
  } else {
    #pragma unroll
    for (int r = 0; r < R; ++r) xoff[r] = (r0 + r) * KX;
  }

  // phase 1: gi += x @ Wi^T
  {
    const float* wp = WiT + j;
    #pragma unroll 2
    for (int k = 0; k < KX; ++k) {
      float wr = wp[0], wz = wp[DH], wn = wp[2*DH];
      wp += 3 * DH;
      #pragma unroll
      for (int r = 0; r < R; ++r) {
        float x = Xin[xoff[r] + k];          // wave-uniform -> s_load
        accr[r]  = fmaf(x, wr, accr[r]);
        accz[r]  = fmaf(x, wz, accz[r]);
        accin[r] = fmaf(x, wn, accin[r]);
      }
    }
  }
  // phase 2: gh += h @ Wh^T
  {
    const float* wp = WhT + j;
    int hoff[R];
    #pragma unroll
    for (int r = 0; r < R; ++r) hoff[r] = (r0 + r) * DH;
    #pragma unroll 2
    for (int k = 0; k < DH; ++k) {
      float wr = wp[0], wz = wp[DH], wn = wp[2*DH];
      wp += 3 * DH;
      #pragma unroll
      for (int r = 0; r < R; ++r) {
        float h = Hprev[hoff[r] + k];        // wave-uniform -> s_load
        accr[r]  = fmaf(h, wr, accr[r]);
        accz[r]  = fmaf(h, wz, accz[r]);
        acchn[r] = fmaf(h, wn, acchn[r]);
      }
    }
  }
  // gates + blend
  #pragma unroll
  for (int r = 0; r < R; ++r) {
    float rg = 1.f / (1.f + expf(-accr[r]));
    float zg = 1.f / (1.f + expf(-accz[r]));
    float n  = tanhf(accin[r] + rg * acchn[r]);
    size_t o = (size_t)(r0 + r) * DH + j;
    float hp = Hprev[o];
    Hnew[o] = (1.f - zg) * n + zg * hp;
  }
}

// ---------------- logits + argmax + EOS bookkeeping ----------------
// one wave per row; lane = vocab id (VOC == 64)
__global__ __launch_bounds__(256) void argmax_kernel(
    const float* __restrict__ H3, const float* __restrict__ h2vT,
    const float* __restrict__ h2v_b,
    int* __restrict__ tok, int* __restrict__ eos,
    int* __restrict__ outi, int t) {
  int lane = threadIdx.x & 63;
  int wave = __builtin_amdgcn_readfirstlane((int)(threadIdx.x >> 6));
  int r = blockIdx.x * 4 + wave;          // grid.x = NROWS/4
  float acc = h2v_b[lane];
  const float* hr = H3 + (size_t)r * DH;  // uniform -> s_load
  #pragma unroll 4
  for (int k = 0; k < DH; ++k)
    acc = fmaf(hr[k], h2vT[(size_t)k * VOC + lane], acc);
  // argmax across 64 lanes; tie -> lowest index (jnp.argmax = first max)
  float v = acc; int idx = lane;
  #pragma unroll
  for (int off = 32; off >= 1; off >>= 1) {
    float v2 = __shfl_xor(v, off);
    int   i2 = __shfl_xor(idx, off);
    if (v2 > v || (v2 == v && i2 < idx)) { v = v2; idx = i2; }
  }
  if (lane == 0) {
    int e = eos[r];
    int x_next = idx;
    outi[(size_t)r * MAXLEN + t] = e ? PAD_T : x_next;
    if (!e && x_next == EOS_T) {
      outi[(size_t)NROWS * MAXLEN + r] = t + 1;  // seq_lens
      eos[r] = 1;
    }
    tok[r] = x_next;  // raw x_next feeds back (reference carries x_next, not tok)
  }
}

// ---------------- host-side orchestration ----------------
extern "C" void kernel_launch(void* const* d_in, const int* in_sizes, int n_in,
                              void* d_out, int out_size, void* d_ws, size_t ws_size,
                              hipStream_t stream) {
  const float* Z      = (const float*)d_in[0];
  const float* emb    = (const float*)d_in[1];
  const float* z2h_w  = (const float*)d_in[2];
  const float* z2h_b  = (const float*)d_in[3];
  const float* W_ih0  = (const float*)d_in[4];
  const float* W_hh0  = (const float*)d_in[5];
  const float* b_ih0  = (const float*)d_in[6];
  const float* b_hh0  = (const float*)d_in[7];
  const float* W_ih1  = (const float*)d_in[8];
  const float* W_hh1  = (const float*)d_in[9];
  const float* b_ih1  = (const float*)d_in[10];
  const float* b_hh1  = (const float*)d_in[11];
  const float* W_ih2  = (const float*)d_in[12];
  const float* W_hh2  = (const float*)d_in[13];
  const float* b_ih2  = (const float*)d_in[14];
  const float* b_hh2  = (const float*)d_in[15];
  const float* h2v_w  = (const float*)d_in[16];
  const float* h2v_b  = (const float*)d_in[17];
  int* outi = (int*)d_out;

  // workspace layout
  float* p = (float*)d_ws;
  float* WiT0 = p; p += (size_t)DZ * 3 * DH;      // [128][1536]
  float* WhT0 = p; p += (size_t)DH * 3 * DH;      // [512][1536]
  float* WiT1 = p; p += (size_t)DH * 3 * DH;
  float* WhT1 = p; p += (size_t)DH * 3 * DH;
  float* WiT2 = p; p += (size_t)DH * 3 * DH;
  float* WhT2 = p; p += (size_t)DH * 3 * DH;
  float* z2hT = p; p += (size_t)DZ * DH;          // [128][512]
  float* h2vT = p; p += (size_t)DH * VOC;         // [512][64]
  float* h1a = p; p += (size_t)NROWS * DH;
  float* h1b = p; p += (size_t)NROWS * DH;
  float* h2a = p; p += (size_t)NROWS * DH;
  float* h2b = p; p += (size_t)NROWS * DH;
  float* h3a = p; p += (size_t)NROWS * DH;
  float* h3b = p; p += (size_t)NROWS * DH;
  int* tokb = (int*)p;
  int* eosb = tokb + NROWS;

  dim3 tb(32, 8);
  transpose_k<<<dim3(DZ/32, (3*DH)/32), tb, 0, stream>>>(W_ih0, WiT0, 3*DH, DZ);
  transpose_k<<<dim3(DH/32, (3*DH)/32), tb, 0, stream>>>(W_hh0, WhT0, 3*DH, DH);
  transpose_k<<<dim3(DH/32, (3*DH)/32), tb, 0, stream>>>(W_ih1, WiT1, 3*DH, DH);
  transpose_k<<<dim3(DH/32, (3*DH)/32), tb, 0, stream>>>(W_hh1, WhT1, 3*DH, DH);
  transpose_k<<<dim3(DH/32, (3*DH)/32), tb, 0, stream>>>(W_ih2, WiT2, 3*DH, DH);
  transpose_k<<<dim3(DH/32, (3*DH)/32), tb, 0, stream>>>(W_hh2, WhT2, 3*DH, DH);
  transpose_k<<<dim3(DZ/32, DH/32),     tb, 0, stream>>>(z2h_w, z2hT, DH, DZ);
  transpose_k<<<dim3(DH/32, VOC/32),    tb, 0, stream>>>(h2v_w, h2vT, VOC, DH);

  init_kernel<<<dim3(NROWS/4, DH/64), 256, 0, stream>>>(
      Z, z2hT, z2h_b, h1a, h2a, h3a, tokb, eosb, outi);

  float* h1p = h1a; float* h1n = h1b;
  float* h2p = h2a; float* h2n = h2b;
  float* h3p = h3a; float* h3n = h3b;
  for (int t = 1; t < MAXLEN; ++t) {
    gru_kernel<DE, true><<<dim3(NROWS/64, DH/64), 256, 0, stream>>>(
        emb, tokb, h1p, WiT0, WhT0, b_ih0, b_hh0, h1n);
    gru_kernel<DH, false><<<dim3(NROWS/64, DH/64), 256, 0, stream>>>(
        h1n, nullptr, h2p, WiT1, WhT1, b_ih1, b_hh1, h2n);
    gru_kernel<DH, false><<<dim3(NROWS/64, DH/64), 256, 0, stream>>>(
        h2n, nullptr, h3p, WiT2, WhT2, b_ih2, b_hh2, h3n);
    argmax_kernel<<<dim3(NROWS/4), 256, 0, stream>>>(
        h3n, h2vT, h2v_b, tokb, eosb, outi, t);
    float* tmp;
    tmp = h1p; h1p = h1n; h1n = tmp;
    tmp = h2p; h2p = h2n; h2n = tmp;
    tmp = h3p; h3p = h3n; h3n = tmp;
  }
}

// Round 2
// 53322.803 us; speedup vs baseline: 1.5971x; 1.5971x over previous
//
#include <hip/hip_runtime.h>
#include <math.h>

#define NROWS 4096
#define DZ    128
#define DH    512
#define VOC   64
#define DE    128
#define MAXLEN 128
#define PAD_T 0
#define SOS_T 1
#define EOS_T 2

// ---------------- repack: in [Rn][K] -> plane P[((k>>2)*Rn + r)*4 + (k&3)] ----
// Lane j then loads float4 = 4 consecutive k's of its row r=j, coalesced across j.
__global__ void repack_k(const float* __restrict__ in, float* __restrict__ out,
                         int Rn, int K) {
  int k = blockIdx.y * 128 + threadIdx.x;
  int r = blockIdx.x;
  out[((size_t)(k >> 2) * Rn + r) * 4 + (k & 3)] = in[(size_t)r * K + k];
}

// ---------------- transpose (for z2h only): in [R][C] -> out [C][R] ----------
__global__ void transpose_k(const float* __restrict__ in, float* __restrict__ out,
                            int R, int C) {
  __shared__ float tile[32][33];
  int cb = blockIdx.x * 32, rb = blockIdx.y * 32;
  int tx = threadIdx.x, ty = threadIdx.y;  // blockDim (32,8)
  #pragma unroll
  for (int i = ty; i < 32; i += 8)
    tile[i][tx] = in[(size_t)(rb + i) * C + (cb + tx)];
  __syncthreads();
  #pragma unroll
  for (int i = ty; i < 32; i += 8)
    out[(size_t)(cb + i) * R + (rb + tx)] = tile[tx][i];
}

// ---------------- G0[v] = emb[v] @ W_ih0^T + b_ih0  (uses packed Wi0) --------
__global__ __launch_bounds__(64) void build_g0(
    const float* __restrict__ emb, const float* __restrict__ P,
    const float* __restrict__ bi, float* __restrict__ G0) {
  int lane = threadIdx.x;
  int j = blockIdx.x * 64 + lane;   // grid.x = DH/64
  int v = blockIdx.y;               // grid.y = VOC
  const size_t KDH = (size_t)DE * DH;
  const float4* e4 = (const float4*)(emb + (size_t)v * DE);
  float ar = bi[j], az = bi[DH + j], an = bi[2 * DH + j];
  for (int k4 = 0; k4 < DE / 4; ++k4) {
    size_t off = ((size_t)k4 * DH + j);
    float4 wr = ((const float4*)P)[off];
    float4 wz = ((const float4*)(P + KDH))[off];
    float4 wn = ((const float4*)(P + 2 * KDH))[off];
    float4 x = e4[k4];
    ar = fmaf(x.x, wr.x, ar); ar = fmaf(x.y, wr.y, ar);
    ar = fmaf(x.z, wr.z, ar); ar = fmaf(x.w, wr.w, ar);
    az = fmaf(x.x, wz.x, az); az = fmaf(x.y, wz.y, az);
    az = fmaf(x.z, wz.z, az); az = fmaf(x.w, wz.w, az);
    an = fmaf(x.x, wn.x, an); an = fmaf(x.y, wn.y, an);
    an = fmaf(x.z, wn.z, an); an = fmaf(x.w, wn.w, an);
  }
  G0[(size_t)v * 3 * DH + j] = ar;
  G0[(size_t)v * 3 * DH + DH + j] = az;
  G0[(size_t)v * 3 * DH + 2 * DH + j] = an;
}

// ---------------- init: h0 = Z @ z2h_w^T + b; state init ----------------
__global__ __launch_bounds__(256) void init_kernel(
    const float* __restrict__ Z, const float* __restrict__ z2hT,
    const float* __restrict__ z2h_b,
    float* __restrict__ h1, float* __restrict__ h2, float* __restrict__ h3,
    int* __restrict__ tok, int* __restrict__ eos, int* __restrict__ outi) {
  int lane = threadIdx.x & 63;
  int wave = __builtin_amdgcn_readfirstlane((int)(threadIdx.x >> 6));
  int r = blockIdx.x * 4 + wave;          // grid.x = NROWS/4
  int j = blockIdx.y * 64 + lane;         // grid.y = DH/64
  float acc = z2h_b[j];
  const float* zr = Z + (size_t)r * DZ;   // wave-uniform -> s_load
  #pragma unroll 4
  for (int k = 0; k < DZ; ++k)
    acc = fmaf(zr[k], z2hT[(size_t)k * DH + j], acc);
  size_t o = (size_t)r * DH + j;
  h1[o] = acc; h2[o] = acc; h3[o] = acc;
  if (blockIdx.y == 0 && lane == 0) {
    tok[r] = SOS_T;
    eos[r] = 0;
    outi[(size_t)r * MAXLEN] = SOS_T;               // X_gen[:,0] = SOS
    outi[(size_t)NROWS * MAXLEN + r] = MAXLEN;      // seq_lens init
  }
}

// ---------------- fused GRU cell layer ----------------
// lane -> gate unit j (64/wave), wave -> 8-row block; grid (NROWS/32, DH/64).
// Weights packed per gate plane [K/4][DH][4]: one coalesced dwordx4/gate/4k.
// Activations: wave-uniform s_load_dwordx4.
template <bool L0>
__global__ __launch_bounds__(256, 4) void gru_kernel(
    const float* __restrict__ Xin,    // [NROWS][DH]   (L1/L2 only)
    const int* __restrict__ tok,      // [NROWS]       (L0 only)
    const float* __restrict__ G0,     // [VOC][3*DH]   (L0 only)
    const float* __restrict__ Hprev,  // [NROWS][DH]
    const float* __restrict__ WiP,    // packed input weights (L1/L2 only)
    const float* __restrict__ WhP,    // packed hidden weights
    const float* __restrict__ bi, const float* __restrict__ bh,
    float* __restrict__ Hnew) {
  constexpr int R = 8;
  const size_t KDH = (size_t)DH * DH;   // per-gate plane size (K=DH)
  int lane = threadIdx.x & 63;
  int wave = __builtin_amdgcn_readfirstlane((int)(threadIdx.x >> 6));
  int r0 = blockIdx.x * (4 * R) + wave * R;  // grid.x = NROWS/32
  int j  = blockIdx.y * 64 + lane;           // grid.y = DH/64

  float accr[R], accz[R], accin[R], acchn[R];
  float bhr = bh[j], bhz = bh[DH + j], bhn = bh[2 * DH + j];
  if constexpr (L0) {
    #pragma unroll
    for (int r = 0; r < R; ++r) {
      const float* g = G0 + (size_t)tok[r0 + r] * (3 * DH);
      accr[r]  = g[j] + bhr;
      accz[r]  = g[DH + j] + bhz;
      accin[r] = g[2 * DH + j];
      acchn[r] = bhn;
    }
  } else {
    float bir = bi[j], biz = bi[DH + j], bin = bi[2 * DH + j];
    #pragma unroll
    for (int r = 0; r < R; ++r) {
      accr[r] = bir + bhr; accz[r] = biz + bhz; accin[r] = bin; acchn[r] = bhn;
    }
    // phase 1: gi += x @ Wi^T
    const float4* x4[R];
    #pragma unroll
    for (int r = 0; r < R; ++r)
      x4[r] = (const float4*)(Xin + (size_t)(r0 + r) * DH);
    #pragma unroll 2
    for (int k4 = 0; k4 < DH / 4; ++k4) {
      size_t off = (size_t)k4 * DH + j;
      float4 wr = ((const float4*)WiP)[off];
      float4 wz = ((const float4*)(WiP + KDH))[off];
      float4 wn = ((const float4*)(WiP + 2 * KDH))[off];
      #pragma unroll
      for (int r = 0; r < R; ++r) {
        float4 x = x4[r][k4];   // wave-uniform -> s_load_dwordx4
        accr[r]  = fmaf(x.x, wr.x, accr[r]);  accr[r]  = fmaf(x.y, wr.y, accr[r]);
        accr[r]  = fmaf(x.z, wr.z, accr[r]);  accr[r]  = fmaf(x.w, wr.w, accr[r]);
        accz[r]  = fmaf(x.x, wz.x, accz[r]);  accz[r]  = fmaf(x.y, wz.y, accz[r]);
        accz[r]  = fmaf(x.z, wz.z, accz[r]);  accz[r]  = fmaf(x.w, wz.w, accz[r]);
        accin[r] = fmaf(x.x, wn.x, accin[r]); accin[r] = fmaf(x.y, wn.y, accin[r]);
        accin[r] = fmaf(x.z, wn.z, accin[r]); accin[r] = fmaf(x.w, wn.w, accin[r]);
      }
    }
  }
  // phase 2: gh += h @ Wh^T
  {
    const float4* h4[R];
    #pragma unroll
    for (int r = 0; r < R; ++r)
      h4[r] = (const float4*)(Hprev + (size_t)(r0 + r) * DH);
    #pragma unroll 2
    for (int k4 = 0; k4 < DH / 4; ++k4) {
      size_t off = (size_t)k4 * DH + j;
      float4 wr = ((const float4*)WhP)[off];
      float4 wz = ((const float4*)(WhP + KDH))[off];
      float4 wn = ((const float4*)(WhP + 2 * KDH))[off];
      #pragma unroll
      for (int r = 0; r < R; ++r) {
        float4 h = h4[r][k4];   // wave-uniform -> s_load_dwordx4
        accr[r]  = fmaf(h.x, wr.x, accr[r]);  accr[r]  = fmaf(h.y, wr.y, accr[r]);
        accr[r]  = fmaf(h.z, wr.z, accr[r]);  accr[r]  = fmaf(h.w, wr.w, accr[r]);
        accz[r]  = fmaf(h.x, wz.x, accz[r]);  accz[r]  = fmaf(h.y, wz.y, accz[r]);
        accz[r]  = fmaf(h.z, wz.z, accz[r]);  accz[r]  = fmaf(h.w, wz.w, accz[r]);
        acchn[r] = fmaf(h.x, wn.x, acchn[r]); acchn[r] = fmaf(h.y, wn.y, acchn[r]);
        acchn[r] = fmaf(h.z, wn.z, acchn[r]); acchn[r] = fmaf(h.w, wn.w, acchn[r]);
      }
    }
  }
  // gates + blend
  #pragma unroll
  for (int r = 0; r < R; ++r) {
    float rg = 1.f / (1.f + expf(-accr[r]));
    float zg = 1.f / (1.f + expf(-accz[r]));
    float n  = tanhf(accin[r] + rg * acchn[r]);
    size_t o = (size_t)(r0 + r) * DH + j;
    float hp = Hprev[o];
    Hnew[o] = (1.f - zg) * n + zg * hp;
  }
}

// ---------------- logits + argmax + EOS bookkeeping ----------------
// one wave per row; lane = vocab id (VOC == 64); h2v packed [k/4][VOC][4]
__global__ __launch_bounds__(256) void argmax_kernel(
    const float* __restrict__ H3, const float* __restrict__ h2vP,
    const float* __restrict__ h2v_b,
    int* __restrict__ tok, int* __restrict__ eos,
    int* __restrict__ outi, int t) {
  int lane = threadIdx.x & 63;
  int wave = __builtin_amdgcn_readfirstlane((int)(threadIdx.x >> 6));
  int r = blockIdx.x * 4 + wave;          // grid.x = NROWS/4
  float acc = h2v_b[lane];
  const float4* h4 = (const float4*)(H3 + (size_t)r * DH);  // uniform -> s_load
  #pragma unroll 2
  for (int k4 = 0; k4 < DH / 4; ++k4) {
    float4 w = ((const float4*)h2vP)[(size_t)k4 * VOC + lane];
    float4 h = h4[k4];
    acc = fmaf(h.x, w.x, acc); acc = fmaf(h.y, w.y, acc);
    acc = fmaf(h.z, w.z, acc); acc = fmaf(h.w, w.w, acc);
  }
  // argmax across 64 lanes; tie -> lowest index (jnp.argmax = first max)
  float v = acc; int idx = lane;
  #pragma unroll
  for (int off = 32; off >= 1; off >>= 1) {
    float v2 = __shfl_xor(v, off);
    int   i2 = __shfl_xor(idx, off);
    if (v2 > v || (v2 == v && i2 < idx)) { v = v2; idx = i2; }
  }
  if (lane == 0) {
    int e = eos[r];
    int x_next = idx;
    outi[(size_t)r * MAXLEN + t] = e ? PAD_T : x_next;
    if (!e && x_next == EOS_T) {
      outi[(size_t)NROWS * MAXLEN + r] = t + 1;  // seq_lens
      eos[r] = 1;
    }
    tok[r] = x_next;  // raw x_next feeds back
  }
}

// ---------------- host-side orchestration ----------------
extern "C" void kernel_launch(void* const* d_in, const int* in_sizes, int n_in,
                              void* d_out, int out_size, void* d_ws, size_t ws_size,
                              hipStream_t stream) {
  const float* Z      = (const float*)d_in[0];
  const float* emb    = (const float*)d_in[1];
  const float* z2h_w  = (const float*)d_in[2];
  const float* z2h_b  = (const float*)d_in[3];
  const float* W_ih0  = (const float*)d_in[4];
  const float* W_hh0  = (const float*)d_in[5];
  const float* b_ih0  = (const float*)d_in[6];
  const float* b_hh0  = (const float*)d_in[7];
  const float* W_ih1  = (const float*)d_in[8];
  const float* W_hh1  = (const float*)d_in[9];
  const float* b_ih1  = (const float*)d_in[10];
  const float* b_hh1  = (const float*)d_in[11];
  const float* W_ih2  = (const float*)d_in[12];
  const float* W_hh2  = (const float*)d_in[13];
  const float* b_ih2  = (const float*)d_in[14];
  const float* b_hh2  = (const float*)d_in[15];
  const float* h2v_w  = (const float*)d_in[16];
  const float* h2v_b  = (const float*)d_in[17];
  int* outi = (int*)d_out;

  // workspace layout (all offsets 16B-aligned)
  float* p = (float*)d_ws;
  float* WiP0 = p; p += (size_t)3 * DE * DH;      // packed, 3 planes of DE*DH
  float* WhP0 = p; p += (size_t)3 * DH * DH;
  float* WiP1 = p; p += (size_t)3 * DH * DH;
  float* WhP1 = p; p += (size_t)3 * DH * DH;
  float* WiP2 = p; p += (size_t)3 * DH * DH;
  float* WhP2 = p; p += (size_t)3 * DH * DH;
  float* G0   = p; p += (size_t)VOC * 3 * DH;     // [64][1536]
  float* z2hT = p; p += (size_t)DZ * DH;
  float* h2vP = p; p += (size_t)DH * VOC;         // packed [k/4][VOC][4]
  float* h1a = p; p += (size_t)NROWS * DH;
  float* h1b = p; p += (size_t)NROWS * DH;
  float* h2a = p; p += (size_t)NROWS * DH;
  float* h2b = p; p += (size_t)NROWS * DH;
  float* h3a = p; p += (size_t)NROWS * DH;
  float* h3b = p; p += (size_t)NROWS * DH;
  int* tokb = (int*)p;
  int* eosb = tokb + NROWS;

  // one-time: repack weights per gate plane
  struct WEnt { const float* src; float* dst; int K; };
  WEnt wl[6] = {
    {W_ih0, WiP0, DE}, {W_hh0, WhP0, DH}, {W_ih1, WiP1, DH},
    {W_hh1, WhP1, DH}, {W_ih2, WiP2, DH}, {W_hh2, WhP2, DH}};
  for (int m = 0; m < 6; ++m)
    for (int g = 0; g < 3; ++g)
      repack_k<<<dim3(DH, wl[m].K / 128), 128, 0, stream>>>(
          wl[m].src + (size_t)g * DH * wl[m].K,
          wl[m].dst + (size_t)g * wl[m].K * DH, DH, wl[m].K);
  repack_k<<<dim3(VOC, DH / 128), 128, 0, stream>>>(h2v_w, h2vP, VOC, DH);
  transpose_k<<<dim3(DZ / 32, DH / 32), dim3(32, 8), 0, stream>>>(z2h_w, z2hT, DH, DZ);
  build_g0<<<dim3(DH / 64, VOC), 64, 0, stream>>>(emb, WiP0, b_ih0, G0);

  init_kernel<<<dim3(NROWS / 4, DH / 64), 256, 0, stream>>>(
      Z, z2hT, z2h_b, h1a, h2a, h3a, tokb, eosb, outi);

  float* h1p = h1a; float* h1n = h1b;
  float* h2p = h2a; float* h2n = h2b;
  float* h3p = h3a; float* h3n = h3b;
  for (int t = 1; t < MAXLEN; ++t) {
    gru_kernel<true><<<dim3(NROWS / 32, DH / 64), 256, 0, stream>>>(
        nullptr, tokb, G0, h1p, nullptr, WhP0, b_ih0, b_hh0, h1n);
    gru_kernel<false><<<dim3(NROWS / 32, DH / 64), 256, 0, stream>>>(
        h1n, nullptr, nullptr, h2p, WiP1, WhP1, b_ih1, b_hh1, h2n);
    gru_kernel<false><<<dim3(NROWS / 32, DH / 64), 256, 0, stream>>>(
        h2n, nullptr, nullptr, h3p, WiP2, WhP2, b_ih2, b_hh2, h3n);
    argmax_kernel<<<dim3(NROWS / 4), 256, 0, stream>>>(
        h3n, h2vP, h2v_b, tokb, eosb, outi, t);
    float* tmp;
    tmp = h1p; h1p = h1n; h1n = tmp;
    tmp = h2p; h2p = h2n; h2n = tmp;
    tmp = h3p; h3p = h3n; h3n = tmp;
  }
}